// Round 1
// baseline (337.268 us; speedup 1.0000x reference)
//
#include <hip/hip_runtime.h>

// LIF scan: x[B,T,N] f32 -> spikes[B,T,N] f32
//   v = v + (x - v)/2 ; s = (v >= 1) ; v = s ? 0 : v
// Sequential in t only; B*N independent chains. Memory-bound streaming
// (~420 MB total traffic -> ~70 us floor at 6 TB/s).

constexpr int B = 64;
constexpr int T = 200;
constexpr int N = 4096;
constexpr int N4 = N / 4;  // 1024 float4 per (b,t) row

__global__ __launch_bounds__(256) void lif_kernel(const float4* __restrict__ x,
                                                  float4* __restrict__ out) {
    const int idx = blockIdx.x * blockDim.x + threadIdx.x;  // 0 .. B*N4-1
    const int b = idx >> 10;         // idx / N4
    const int n = idx & (N4 - 1);    // idx % N4

    const float4* __restrict__ xp = x + (size_t)b * (T * N4) + n;
    float4* __restrict__ op = out + (size_t)b * (T * N4) + n;

    float4 v = {0.0f, 0.0f, 0.0f, 0.0f};

#pragma unroll 8
    for (int t = 0; t < T; ++t) {
        const float4 xv = xp[t * N4];
        float4 s;
        // v = v + (x - v) * 0.5f  -- *0.5 is exact, so with or without fma
        // contraction this matches the numpy f32 reference bit-for-bit.
        v.x = v.x + (xv.x - v.x) * 0.5f;
        v.y = v.y + (xv.y - v.y) * 0.5f;
        v.z = v.z + (xv.z - v.z) * 0.5f;
        v.w = v.w + (xv.w - v.w) * 0.5f;

        s.x = (v.x >= 1.0f) ? 1.0f : 0.0f;
        s.y = (v.y >= 1.0f) ? 1.0f : 0.0f;
        s.z = (v.z >= 1.0f) ? 1.0f : 0.0f;
        s.w = (v.w >= 1.0f) ? 1.0f : 0.0f;

        v.x = (v.x >= 1.0f) ? 0.0f : v.x;
        v.y = (v.y >= 1.0f) ? 0.0f : v.y;
        v.z = (v.z >= 1.0f) ? 0.0f : v.z;
        v.w = (v.w >= 1.0f) ? 0.0f : v.w;

        op[t * N4] = s;
    }
}

extern "C" void kernel_launch(void* const* d_in, const int* in_sizes, int n_in,
                              void* d_out, int out_size, void* d_ws, size_t ws_size,
                              hipStream_t stream) {
    const float4* x = (const float4*)d_in[0];  // [B,T,N] f32
    // d_in[1] (threshold, 1xN) is unused by the reference math.
    float4* out = (float4*)d_out;

    const int threads = B * N4;        // 65536 chains (float4 granularity)
    const int block = 256;
    const int grid = threads / block;  // 256 blocks
    lif_kernel<<<grid, block, 0, stream>>>(x, out);
}